// Round 10
// baseline (192.292 us; speedup 1.0000x reference)
//
#include <hip/hip_runtime.h>
#include <hip/hip_bf16.h>

#define NN 4096
#define KIN 256
#define HF 512
#define NHD 4
#define OF 128
#define JP 4160            // padded hbT row stride (8320 B: non-pow2 channel spread)

typedef __bf16 bf16x8 __attribute__((ext_vector_type(8)));
typedef __bf16 bf16x4 __attribute__((ext_vector_type(4)));
typedef float f32x4 __attribute__((ext_vector_type(4)));
typedef _Float16 f16x4 __attribute__((ext_vector_type(4)));

// async 16B/lane global->LDS: dest = wave-uniform LDS base + lane*16,
// src = per-lane global address. In-flight state lives in the vmem queue,
// NOT in VGPRs (the 128-reg allocator cap made reg-based MLP impossible).
__device__ __forceinline__ void glds16(const void* g, void* l) {
    __builtin_amdgcn_global_load_lds(
        (const __attribute__((address_space(1))) void*)g,
        (__attribute__((address_space(3))) void*)l, 16, 0, 0);
}

// ---------------- K0: WT[c][k] = (bf16)W[k][c], LDS-tiled ----------------
__global__ __launch_bounds__(256) void k_transpose_w(const float* __restrict__ W,
                                                     __bf16* __restrict__ WT) {
    __shared__ __bf16 tl[64][65];
    int k0 = blockIdx.x * 64, c0 = blockIdx.y * 64;
    #pragma unroll
    for (int it = 0; it < 16; ++it) {
        int idx = it * 256 + threadIdx.x;
        int kk = idx >> 6, cc = idx & 63;
        tl[kk][cc] = (__bf16)W[(size_t)(k0 + kk) * HF + c0 + cc];
    }
    __syncthreads();
    #pragma unroll
    for (int it = 0; it < 16; ++it) {
        int idx = it * 256 + threadIdx.x;
        int cc = idx >> 6, kk = idx & 63;
        WT[(size_t)(c0 + cc) * KIN + k0 + kk] = tl[kk][cc];
    }
}

// ------- K1: gemm (hbT) + fused ci/cj. grid (256 node-tiles, 4 h). -------
// UNCHANGED (will surface in top-5 with counters once k_attn shrinks).
__global__ __launch_bounds__(256) void k_gemm_h(const float* __restrict__ x,
                                                const __bf16* __restrict__ WT,
                                                const float* __restrict__ ai,
                                                const float* __restrict__ aj,
                                                __bf16* __restrict__ hbT,
                                                float* __restrict__ ci,
                                                float* __restrict__ cj) {
    __shared__ float credi[4][16], credj[4][16];
    int tid = threadIdx.x, lane = tid & 63, w = tid >> 6;
    int r = lane & 15, q = lane >> 4;
    int m0 = blockIdx.x * 16;
    int h = blockIdx.y;
    int c0 = h * 128 + w * 32;
    f32x4 acc[2];
    #pragma unroll
    for (int nt = 0; nt < 2; ++nt) acc[nt] = (f32x4){0.f, 0.f, 0.f, 0.f};
    const float* xp = x + (size_t)(m0 + r) * KIN + q * 8;
    #pragma unroll
    for (int kk = 0; kk < 8; ++kk) {
        float4 xa = *(const float4*)(xp + kk * 32);
        float4 xb = *(const float4*)(xp + kk * 32 + 4);
        bf16x8 af;
        af[0] = (__bf16)xa.x; af[1] = (__bf16)xa.y; af[2] = (__bf16)xa.z; af[3] = (__bf16)xa.w;
        af[4] = (__bf16)xb.x; af[5] = (__bf16)xb.y; af[6] = (__bf16)xb.z; af[7] = (__bf16)xb.w;
        #pragma unroll
        for (int nt = 0; nt < 2; ++nt) {
            bf16x8 bf = *(const bf16x8*)(WT + (size_t)(c0 + nt * 16 + r) * KIN + kk * 32 + q * 8);
            acc[nt] = __builtin_amdgcn_mfma_f32_16x16x32_bf16(af, bf, acc[nt], 0, 0, 0);
        }
    }
    float pi[4] = {0.f, 0.f, 0.f, 0.f}, pj[4] = {0.f, 0.f, 0.f, 0.f};
    #pragma unroll
    for (int nt = 0; nt < 2; ++nt) {
        int c = c0 + nt * 16 + r;
        float av = ai[c], jv = aj[c];
        bf16x4 o;
        #pragma unroll
        for (int e = 0; e < 4; ++e) {
            o[e] = (__bf16)acc[nt][e];
            pi[e] += av * acc[nt][e];
            pj[e] += jv * acc[nt][e];
        }
        *(bf16x4*)(hbT + (size_t)c * JP + m0 + q * 4) = o;
    }
    #pragma unroll
    for (int off = 1; off < 16; off <<= 1)
        #pragma unroll
        for (int e = 0; e < 4; ++e) {
            pi[e] += __shfl_xor(pi[e], off);
            pj[e] += __shfl_xor(pj[e], off);
        }
    if (r == 0)
        #pragma unroll
        for (int e = 0; e < 4; ++e) {
            credi[w][q * 4 + e] = pi[e];
            credj[w][q * 4 + e] = pj[e];
        }
    __syncthreads();
    if (tid < 16) {
        ci[h * NN + m0 + tid] = credi[0][tid] + credi[1][tid] + credi[2][tid] + credi[3][tid];
    } else if (tid >= 64 && tid < 80) {
        int nl = tid - 64;
        cj[h * NN + m0 + nl] = credj[0][nl] + credj[1][nl] + credj[2][nl] + credj[3][nl];
    }
}

// ---------------- K3: fused attention, DEPTH-2 async LDS pipeline ----------------
// ROUND-10: round 9 (depth-1 dbuf) cut 104->75us but left ~3K cy/chunk of
// exposed HBM latency (stage issued only 1 chunk ahead of use).
//   - TRIPLE buffer (V 96KB + adj 24KB), stage issued 2 chunks ahead:
//     latency cover = 2 full chunk-times (~4-5K cy) > HBM ~900-1500 cy.
//   - cj staged ONCE in prologue into cjt LDS (16KB): per-chunk vmem is now
//     EXACTLY the 5 stage glds -> clean counted vmcnt: steady 10, tail 5/0.
//   - prologue drains civ/cjt with one vmcnt(0) (once, off the critical path)
//     so the loop's vmcnt domain contains only stage loads.
//   - LDS total 136 KB (round-0 ran 153 KB -> size safe). 1 block/CU.
//   - barriers unchanged: end-of-iter barrier guards write-after-read
//     (iter c+1 writes buf[(c+3)%3] == buf[c%3], read during iter c).
__global__ __launch_bounds__(512) void k_attn(const float* __restrict__ adj,
                                              const __bf16* __restrict__ hbT,
                                              const float* __restrict__ ci,
                                              const float* __restrict__ cj,
                                              _Float16* __restrict__ num,
                                              float* __restrict__ den,
                                              int jmask, int jsh) {
    __shared__ __bf16 vt[3][512][32];    // [buf][h*128+ch][j-slot swz]  96 KB
    __shared__ float  ats[3][64][32];    // [buf][i-local][j-slot swz]   24 KB
    __shared__ float  cjt[NHD][1024];    // whole cj slice, staged once  16 KB
    int tid = threadIdx.x, lane = tid & 63, w = tid >> 6;
    int h = w & 3, rg = w >> 2;
    int m = lane & 15, q = lane >> 4;
    int bid = blockIdx.x;
    int js = bid & jmask;
    int i0 = (bid >> jsh) << 6;
    int jb = js << (12 - jsh);          // slice width = NN >> jsh (=1024)
    int nch = 1 << (7 - jsh);           // chunks of 32 j per slice (=32)

    // ---- staging source pointers (per-lane; advance 32 elems/chunk) ----
    // V: wave w stages rows (w*4+k)*16..+15; lane -> row t = base+(lane>>2),
    //    phys slot lane&3, source j-slot = (lane&3)^(t&3) (inverse swizzle).
    const __bf16* vS[4];
    #pragma unroll
    for (int k = 0; k < 4; ++k) {
        int t = (w * 4 + k) * 16 + (lane >> 2);
        vS[k] = hbT + (size_t)t * JP + jb + (((lane & 3) ^ (t & 3)) * 8);
    }
    // adj: wave w stages rows w*8..w*8+7; lane -> row il = w*8+(lane>>3),
    //      phys slot lane&7, source j-slot = (lane&7)^(il&7).
    int il = w * 8 + (lane >> 3);
    const float* aS = adj + (size_t)(i0 + il) * NN + jb + (((lane & 7) ^ (il & 7)) * 4);

    // ---- prologue ----
    float civ0 = ci[h * NN + i0 + rg * 32 + m];
    float civ1 = ci[h * NN + i0 + rg * 32 + 16 + m];
    // cjt: 16 KB = 16 x 1KB blocks; wave w stages blocks 2w, 2w+1.
    // block b: h = b>>2, joff = (b&3)*256; lane covers floats 4*lane..+3.
    #pragma unroll
    for (int k = 0; k < 2; ++k) {
        int b = 2 * w + k;
        int bh = b >> 2, joff = (b & 3) * 256;
        glds16(cj + (size_t)bh * NN + jb + joff + 4 * lane, &cjt[bh][joff]);
    }
    asm volatile("s_waitcnt vmcnt(0)" ::: "memory");   // drain civ+cjt (once)
    // stage chunks 0 and 1 into bufs 0 and 1
    #pragma unroll
    for (int k = 0; k < 4; ++k) glds16(vS[k], &vt[0][(w * 4 + k) * 16][0]);
    glds16(aS, &ats[0][w * 8][0]);
    #pragma unroll
    for (int k = 0; k < 4; ++k) glds16(vS[k] + 32, &vt[1][(w * 4 + k) * 16][0]);
    glds16(aS + 32, &ats[1][w * 8][0]);

    f32x4 acc[2][8];
    #pragma unroll
    for (int g = 0; g < 2; ++g)
        #pragma unroll
        for (int nt = 0; nt < 8; ++nt) acc[g][nt] = (f32x4){0.f, 0.f, 0.f, 0.f};
    float den0 = 0.f, den1 = 0.f;

    int ir0 = rg * 32 + m;                   // g=0 LDS adj row; g=1 is +16
    int sA0 = ((2 * q + 0) ^ (m & 7)) * 4;   // adj phys slot offsets (floats)
    int sA1 = ((2 * q + 1) ^ (m & 7)) * 4;
    int sV  = (q ^ (m & 3)) * 8;             // V phys slot offset (bf16)

    for (int c = 0; c < nch; ++c) {
        int cb = c % 3;
        // ---- issue stage(c+2), counted wait for stage(c) ----
        if (c + 2 < nch) {
            int nb = (c + 2) % 3;
            #pragma unroll
            for (int k = 0; k < 4; ++k)
                glds16(vS[k] + (size_t)(c + 2) * 32, &vt[nb][(w * 4 + k) * 16][0]);
            glds16(aS + (size_t)(c + 2) * 32, &ats[nb][w * 8][0]);
            asm volatile("s_waitcnt vmcnt(10)" ::: "memory");  // c+1,c+2 in flight
        } else if (c + 1 < nch) {
            asm volatile("s_waitcnt vmcnt(5)" ::: "memory");   // c+1 in flight
        } else {
            asm volatile("s_waitcnt vmcnt(0)" ::: "memory");   // tail drain
        }
        __builtin_amdgcn_s_barrier();                          // buf[cb] staged
        asm volatile("" ::: "memory");                         // no ds_read hoists

        // ---- adj fragments from LDS (2-way = free) ----
        float4 x00 = *(const float4*)&ats[cb][ir0][sA0];
        float4 x01 = *(const float4*)&ats[cb][ir0][sA1];
        float4 x10 = *(const float4*)&ats[cb][ir0 + 16][sA0];
        float4 x11 = *(const float4*)&ats[cb][ir0 + 16][sA1];
        // cj from LDS (same addr across q-group -> broadcast, free)
        float4 cA = *(const float4*)&cjt[h][c * 32 + q * 8];
        float4 cB = *(const float4*)&cjt[h][c * 32 + q * 8 + 4];
        float ccv[8];
        ccv[0] = cA.x; ccv[1] = cA.y; ccv[2] = cA.z; ccv[3] = cA.w;
        ccv[4] = cB.x; ccv[5] = cB.y; ccv[6] = cB.z; ccv[7] = cB.w;
        float aa0[8], aa1[8];
        aa0[0] = x00.x; aa0[1] = x00.y; aa0[2] = x00.z; aa0[3] = x00.w;
        aa0[4] = x01.x; aa0[5] = x01.y; aa0[6] = x01.z; aa0[7] = x01.w;
        aa1[0] = x10.x; aa1[1] = x10.y; aa1[2] = x10.z; aa1[3] = x10.w;
        aa1[4] = x11.x; aa1[5] = x11.y; aa1[6] = x11.z; aa1[7] = x11.w;

        bf16x8 af0, af1;
        #pragma unroll
        for (int u = 0; u < 8; ++u) {
            float a = aa0[u];
            float s = civ0 + ccv[u];
            s = fmaxf(s, s * 0.2f);     // leaky_relu
            s *= a;
            float p = __expf(s);        // s in ~[-4,4]: shift-free softmax safe
            den0 += p;
            af0[u] = (__bf16)(p * a);
        }
        #pragma unroll
        for (int u = 0; u < 8; ++u) {
            float a = aa1[u];
            float s = civ1 + ccv[u];
            s = fmaxf(s, s * 0.2f);
            s *= a;
            float p = __expf(s);
            den1 += p;
            af1[u] = (__bf16)(p * a);
        }
        // ---- MFMA: V fragments from LDS (4-way, ~95cy/chunk/SIMD) ----
        #pragma unroll
        for (int nt = 0; nt < 8; ++nt) {
            bf16x8 bfv = *(const bf16x8*)&vt[cb][h * 128 + nt * 16 + m][sV];
            acc[0][nt] = __builtin_amdgcn_mfma_f32_16x16x32_bf16(af0, bfv, acc[0][nt], 0, 0, 0);
            acc[1][nt] = __builtin_amdgcn_mfma_f32_16x16x32_bf16(af1, bfv, acc[1][nt], 0, 0, 0);
        }
        asm volatile("" ::: "memory");                         // no ds_read sinks
        __builtin_amdgcn_s_barrier();                          // done with buf[cb]
    }
    // den over q-partitions (j mod 32): lanes {m, m+16, m+32, m+48}
    den0 += __shfl_xor(den0, 16); den0 += __shfl_xor(den0, 32);
    den1 += __shfl_xor(den1, 16); den1 += __shfl_xor(den1, 32);
    if (lane < 16) {
        float* dp = den + ((size_t)js * NHD + h) * NN + i0 + rg * 32;
        dp[lane] = den0;
        dp[16 + lane] = den1;
    }
    // num partials (fp16): C/D row = q*4+reg (i-local), col = nt*16+m (f)
    #pragma unroll
    for (int g = 0; g < 2; ++g)
        #pragma unroll
        for (int nt = 0; nt < 8; ++nt)
            #pragma unroll
            for (int reg = 0; reg < 4; ++reg) {
                int i = i0 + rg * 32 + g * 16 + q * 4 + reg;
                num[((size_t)js * NN + i) * HF + h * OF + nt * 16 + m] =
                    (_Float16)acc[g][nt][reg];
            }
}

// ---------------- K4: reduce jsn partials, divide, +bias, fp32 out ---------
__global__ __launch_bounds__(256) void k_reduce(const _Float16* __restrict__ num,
                                               const float* __restrict__ den,
                                               const float* __restrict__ bias,
                                               float* __restrict__ out,
                                               int jsn) {
    int g = blockIdx.x * 256 + threadIdx.x;    // NN*HF/4 groups
    int i = g >> 7, c4 = (g & 127) << 2;
    int h = c4 >> 7;
    float s0 = 0.f, s1 = 0.f, s2 = 0.f, s3 = 0.f, d = 0.f;
    for (int js = 0; js < jsn; ++js) {
        f16x4 v = *(const f16x4*)(num + ((size_t)js * NN + i) * HF + c4);
        s0 += (float)v[0]; s1 += (float)v[1]; s2 += (float)v[2]; s3 += (float)v[3];
        d += den[((size_t)js * NHD + h) * NN + i];
    }
    float inv = 1.0f / d;
    float4 b = *(const float4*)(bias + c4);
    float4 o;
    o.x = s0 * inv + b.x; o.y = s1 * inv + b.y;
    o.z = s2 * inv + b.z; o.w = s3 * inv + b.w;
    *(float4*)(out + (size_t)i * HF + c4) = o;
}

extern "C" void kernel_launch(void* const* d_in, const int* in_sizes, int n_in,
                              void* d_out, int out_size, void* d_ws, size_t ws_size,
                              hipStream_t stream) {
    const float* x    = (const float*)d_in[0];
    const float* adj  = (const float*)d_in[1];
    const float* W    = (const float*)d_in[2];
    const float* ai   = (const float*)d_in[3];
    const float* aj   = (const float*)d_in[4];
    const float* bias = (const float*)d_in[5];
    float* out = (float*)d_out;

    int jsn = 4, jsh = 2;   // grid 256 = 1 block/CU (LDS-forced anyway)

    char* ws = (char*)d_ws;
    __bf16*   hbT = (__bf16*)(ws);                               // 4,259,840 B used
    float*    ci  = (float*)(ws + 4456448);                      // 64 KB
    float*    cj  = (float*)(ws + 4521984);                      // 64 KB
    __bf16*   WT  = (__bf16*)(ws + 4587520);                     // 256 KB
    float*    den = (float*)(ws + 4849664);                      // jsn*64 KB
    _Float16* num = (_Float16*)(ws + 4849664 + (size_t)jsn * 65536);  // jsn*4 MB

    k_transpose_w<<<dim3(4, 8), 256, 0, stream>>>(W, WT);
    k_gemm_h<<<dim3(256, 4), 256, 0, stream>>>(x, WT, ai, aj, hbT, ci, cj);
    k_attn<<<jsn * 64, 512, 0, stream>>>(adj, hbT, ci, cj, num, den, jsn - 1, jsh);
    k_reduce<<<2048, 256, 0, stream>>>(num, den, bias, out, jsn);
}

// Round 11
// 174.196 us; speedup vs baseline: 1.1039x; 1.1039x over previous
//
#include <hip/hip_runtime.h>
#include <hip/hip_bf16.h>

#define NN 4096
#define KIN 256
#define HF 512
#define NHD 4
#define OF 128
#define JP 4160            // padded hbT row stride (8320 B: non-pow2 channel spread)

typedef __bf16 bf16x8 __attribute__((ext_vector_type(8)));
typedef __bf16 bf16x4 __attribute__((ext_vector_type(4)));
typedef float f32x4 __attribute__((ext_vector_type(4)));
typedef _Float16 f16x4 __attribute__((ext_vector_type(4)));

// async 16B/lane global->LDS: dest = wave-uniform LDS base + lane*16,
// src = per-lane global address. In-flight state lives in the vmem queue,
// NOT in VGPRs (the ~128-reg allocator ceiling re-serializes reg-based MLP).
__device__ __forceinline__ void glds16(const void* g, void* l) {
    __builtin_amdgcn_global_load_lds(
        (const __attribute__((address_space(1))) void*)g,
        (__attribute__((address_space(3))) void*)l, 16, 0, 0);
}

// ---------------- K0: W -> WTp, FRAGMENT-MAJOR pack ----------------
// ROUND-11: WTp[((t*8+kk)*64+lane)*8 + e] = W[kk*32+(lane>>4)*8+e][t*16+(lane&15)]
// i.e. exactly the bf16x8 B-fragment K1's wave needs for (c-tile t, k-chunk kk),
// laid out so the 64 lanes of one fragment are CONTIGUOUS (1 KB burst).
// Same traffic as the old transpose; write side emits coalesced 16B/thread.
__global__ __launch_bounds__(256) void k_transpose_w(const float* __restrict__ W,
                                                     __bf16* __restrict__ WTp) {
    __shared__ __bf16 tl[64][65];
    int k0 = blockIdx.x * 64, c0 = blockIdx.y * 64;
    #pragma unroll
    for (int it = 0; it < 16; ++it) {
        int idx = it * 256 + threadIdx.x;
        int kk = idx >> 6, cc = idx & 63;
        tl[kk][cc] = (__bf16)W[(size_t)(k0 + kk) * HF + c0 + cc];
    }
    __syncthreads();
    int lane = threadIdx.x & 63, f0 = threadIdx.x >> 6;   // f0 = local c-tile 0..3
    int q = lane >> 4, r = lane & 15;
    #pragma unroll
    for (int kkf = 0; kkf < 2; ++kkf) {                   // two 32-k chunks in tile
        bf16x8 o;
        #pragma unroll
        for (int e = 0; e < 8; ++e)
            o[e] = tl[kkf * 32 + q * 8 + e][f0 * 16 + r];
        int t_g = (c0 >> 4) + f0;
        int kk_g = (k0 >> 5) + kkf;
        *(bf16x8*)(WTp + ((size_t)(t_g * 8 + kk_g) * 64 + lane) * 8) = o;
    }
}

// ------- K1: gemm (hbT) + fused ci/cj — ROUND-11 de-divergence rewrite -------
// grid (256 node-tiles, 4 h), 256 thr = 4 waves, wave w: c0 = h*128 + w*32.
// Old version: every x/WT load touched 16 scattered cache lines, re-serialized
// under the 128-VGPR ceiling -> ~100us (20x off roofline) ALL SESSION (hidden
// below k_attn in top-5). Fix = the k_attn round-9 mechanism:
//   - x tile (16 rows x 256) staged ONCE via 4 coalesced glds16/wave into LDS
//     (row pad 257 -> ~2-way banks, free); fragments read from LDS at 12cy.
//   - WT fragments from WTp: contiguous 1KB bursts (fragment-major pack).
// Per-kk working set ~30 regs -> allocator ceiling irrelevant; 16+ waves/CU.
__global__ __launch_bounds__(256) void k_gemm_h(const float* __restrict__ x,
                                                const __bf16* __restrict__ WTp,
                                                const float* __restrict__ ai,
                                                const float* __restrict__ aj,
                                                __bf16* __restrict__ hbT,
                                                float* __restrict__ ci,
                                                float* __restrict__ cj) {
    __shared__ float xs[16][257];
    __shared__ float credi[4][16], credj[4][16];
    int tid = threadIdx.x, lane = tid & 63, w = tid >> 6;
    int r = lane & 15, q = lane >> 4;
    int m0 = blockIdx.x * 16;
    int h = blockIdx.y;

    // stage x tile: 4 rows/wave, each one contiguous 1KB (lane covers 16B)
    #pragma unroll
    for (int k = 0; k < 4; ++k) {
        int row = w * 4 + k;
        glds16(x + (size_t)(m0 + row) * KIN + 4 * lane, &xs[row][0]);
    }
    asm volatile("s_waitcnt vmcnt(0)" ::: "memory");
    __syncthreads();

    f32x4 acc[2];
    #pragma unroll
    for (int nt = 0; nt < 2; ++nt) acc[nt] = (f32x4){0.f, 0.f, 0.f, 0.f};
    // fragment base for (t = h*8 + w*2, kk = 0); +nt -> +4096 elems, +kk -> +512
    const __bf16* wp = WTp + ((size_t)(h * 8 + w * 2) * 8 * 64 + lane) * 8;
    #pragma unroll
    for (int kk = 0; kk < 8; ++kk) {
        float4 xa = *(const float4*)&xs[r][kk * 32 + q * 8];
        float4 xb = *(const float4*)&xs[r][kk * 32 + q * 8 + 4];
        bf16x8 af;
        af[0] = (__bf16)xa.x; af[1] = (__bf16)xa.y; af[2] = (__bf16)xa.z; af[3] = (__bf16)xa.w;
        af[4] = (__bf16)xb.x; af[5] = (__bf16)xb.y; af[6] = (__bf16)xb.z; af[7] = (__bf16)xb.w;
        #pragma unroll
        for (int nt = 0; nt < 2; ++nt) {
            bf16x8 bf = *(const bf16x8*)(wp + nt * 4096 + kk * 512);
            acc[nt] = __builtin_amdgcn_mfma_f32_16x16x32_bf16(af, bf, acc[nt], 0, 0, 0);
        }
    }
    float pi[4] = {0.f, 0.f, 0.f, 0.f}, pj[4] = {0.f, 0.f, 0.f, 0.f};
    #pragma unroll
    for (int nt = 0; nt < 2; ++nt) {
        int c = h * 128 + w * 32 + nt * 16 + r;
        float av = ai[c], jv = aj[c];
        bf16x4 o;
        #pragma unroll
        for (int e = 0; e < 4; ++e) {
            o[e] = (__bf16)acc[nt][e];
            pi[e] += av * acc[nt][e];
            pj[e] += jv * acc[nt][e];
        }
        *(bf16x4*)(hbT + (size_t)c * JP + m0 + q * 4) = o;
    }
    #pragma unroll
    for (int off = 1; off < 16; off <<= 1)
        #pragma unroll
        for (int e = 0; e < 4; ++e) {
            pi[e] += __shfl_xor(pi[e], off);
            pj[e] += __shfl_xor(pj[e], off);
        }
    if (r == 0)
        #pragma unroll
        for (int e = 0; e < 4; ++e) {
            credi[w][q * 4 + e] = pi[e];
            credj[w][q * 4 + e] = pj[e];
        }
    __syncthreads();
    if (tid < 16) {
        ci[h * NN + m0 + tid] = credi[0][tid] + credi[1][tid] + credi[2][tid] + credi[3][tid];
    } else if (tid >= 64 && tid < 80) {
        int nl = tid - 64;
        cj[h * NN + m0 + nl] = credj[0][nl] + credj[1][nl] + credj[2][nl] + credj[3][nl];
    }
}

// ---------------- K3: fused attention — REVERTED to round-9 (measured 75us) ----------------
// Depth-2 (round 10) was neutral-to-worse; double buffer + depth-1 is the best
// measured config for this structure.
__global__ __launch_bounds__(512) void k_attn(const float* __restrict__ adj,
                                              const __bf16* __restrict__ hbT,
                                              const float* __restrict__ ci,
                                              const float* __restrict__ cj,
                                              _Float16* __restrict__ num,
                                              float* __restrict__ den,
                                              int jmask, int jsh) {
    __shared__ __bf16 vt[2][512][32];    // [buf][h*128+ch][j-slot swizzled]
    __shared__ float  ats[2][64][32];    // [buf][i-local][j-slot swizzled]
    int tid = threadIdx.x, lane = tid & 63, w = tid >> 6;
    int h = w & 3, rg = w >> 2;
    int m = lane & 15, q = lane >> 4;
    int bid = blockIdx.x;
    int js = bid & jmask;
    int i0 = (bid >> jsh) << 6;
    int jb = js << (12 - jsh);          // slice width = NN >> jsh (=1024)
    int nch = 1 << (7 - jsh);           // chunks of 32 j per slice (=32)

    const __bf16* vS[4];
    #pragma unroll
    for (int k = 0; k < 4; ++k) {
        int t = (w * 4 + k) * 16 + (lane >> 2);
        vS[k] = hbT + (size_t)t * JP + jb + (((lane & 3) ^ (t & 3)) * 8);
    }
    int il = w * 8 + (lane >> 3);
    const float* aS = adj + (size_t)(i0 + il) * NN + jb + (((lane & 7) ^ (il & 7)) * 4);
    const float* cjsrc = cj + (size_t)h * NN + jb + q * 8;

    float civ0 = ci[h * NN + i0 + rg * 32 + m];
    float civ1 = ci[h * NN + i0 + rg * 32 + 16 + m];

    f32x4 acc[2][8];
    #pragma unroll
    for (int g = 0; g < 2; ++g)
        #pragma unroll
        for (int nt = 0; nt < 8; ++nt) acc[g][nt] = (f32x4){0.f, 0.f, 0.f, 0.f};
    float den0 = 0.f, den1 = 0.f;

    #pragma unroll
    for (int k = 0; k < 4; ++k) glds16(vS[k], &vt[0][(w * 4 + k) * 16][0]);
    glds16(aS, &ats[0][w * 8][0]);
    float4 pc0 = *(const float4*)(cjsrc);
    float4 pc1 = *(const float4*)(cjsrc + 4);

    int ir0 = rg * 32 + m;
    int sA0 = ((2 * q + 0) ^ (m & 7)) * 4;
    int sA1 = ((2 * q + 1) ^ (m & 7)) * 4;
    int sV  = (q ^ (m & 3)) * 8;

    for (int c = 0; c < nch; ++c) {
        int cb = c & 1, nb = cb ^ 1;
        if (c + 1 < nch) {
            #pragma unroll
            for (int k = 0; k < 4; ++k)
                glds16(vS[k] + (size_t)(c + 1) * 32, &vt[nb][(w * 4 + k) * 16][0]);
            glds16(aS + (size_t)(c + 1) * 32, &ats[nb][w * 8][0]);
            asm volatile("s_waitcnt vmcnt(7)" ::: "memory");
        } else {
            asm volatile("s_waitcnt vmcnt(0)" ::: "memory");
        }
        __builtin_amdgcn_s_barrier();
        asm volatile("" ::: "memory");

        float4 x00 = *(const float4*)&ats[cb][ir0][sA0];
        float4 x01 = *(const float4*)&ats[cb][ir0][sA1];
        float4 x10 = *(const float4*)&ats[cb][ir0 + 16][sA0];
        float4 x11 = *(const float4*)&ats[cb][ir0 + 16][sA1];
        float ccv[8];
        ccv[0] = pc0.x; ccv[1] = pc0.y; ccv[2] = pc0.z; ccv[3] = pc0.w;
        ccv[4] = pc1.x; ccv[5] = pc1.y; ccv[6] = pc1.z; ccv[7] = pc1.w;
        float aa0[8], aa1[8];
        aa0[0] = x00.x; aa0[1] = x00.y; aa0[2] = x00.z; aa0[3] = x00.w;
        aa0[4] = x01.x; aa0[5] = x01.y; aa0[6] = x01.z; aa0[7] = x01.w;
        aa1[0] = x10.x; aa1[1] = x10.y; aa1[2] = x10.z; aa1[3] = x10.w;
        aa1[4] = x11.x; aa1[5] = x11.y; aa1[6] = x11.z; aa1[7] = x11.w;

        bf16x8 af0, af1;
        #pragma unroll
        for (int u = 0; u < 8; ++u) {
            float a = aa0[u];
            float s = civ0 + ccv[u];
            s = fmaxf(s, s * 0.2f);     // leaky_relu
            s *= a;
            float p = __expf(s);        // s in ~[-4,4]: shift-free softmax safe
            den0 += p;
            af0[u] = (__bf16)(p * a);
        }
        #pragma unroll
        for (int u = 0; u < 8; ++u) {
            float a = aa1[u];
            float s = civ1 + ccv[u];
            s = fmaxf(s, s * 0.2f);
            s *= a;
            float p = __expf(s);
            den1 += p;
            af1[u] = (__bf16)(p * a);
        }
        if (c + 1 < nch) {
            pc0 = *(const float4*)(cjsrc + (c + 1) * 32);
            pc1 = *(const float4*)(cjsrc + (c + 1) * 32 + 4);
        }
        #pragma unroll
        for (int nt = 0; nt < 8; ++nt) {
            bf16x8 bfv = *(const bf16x8*)&vt[cb][h * 128 + nt * 16 + m][sV];
            acc[0][nt] = __builtin_amdgcn_mfma_f32_16x16x32_bf16(af0, bfv, acc[0][nt], 0, 0, 0);
            acc[1][nt] = __builtin_amdgcn_mfma_f32_16x16x32_bf16(af1, bfv, acc[1][nt], 0, 0, 0);
        }
        asm volatile("" ::: "memory");
        __builtin_amdgcn_s_barrier();
    }
    den0 += __shfl_xor(den0, 16); den0 += __shfl_xor(den0, 32);
    den1 += __shfl_xor(den1, 16); den1 += __shfl_xor(den1, 32);
    if (lane < 16) {
        float* dp = den + ((size_t)js * NHD + h) * NN + i0 + rg * 32;
        dp[lane] = den0;
        dp[16 + lane] = den1;
    }
    #pragma unroll
    for (int g = 0; g < 2; ++g)
        #pragma unroll
        for (int nt = 0; nt < 8; ++nt)
            #pragma unroll
            for (int reg = 0; reg < 4; ++reg) {
                int i = i0 + rg * 32 + g * 16 + q * 4 + reg;
                num[((size_t)js * NN + i) * HF + h * OF + nt * 16 + m] =
                    (_Float16)acc[g][nt][reg];
            }
}

// ---------------- K4: reduce jsn partials, divide, +bias, fp32 out ---------
__global__ __launch_bounds__(256) void k_reduce(const _Float16* __restrict__ num,
                                               const float* __restrict__ den,
                                               const float* __restrict__ bias,
                                               float* __restrict__ out,
                                               int jsn) {
    int g = blockIdx.x * 256 + threadIdx.x;    // NN*HF/4 groups
    int i = g >> 7, c4 = (g & 127) << 2;
    int h = c4 >> 7;
    float s0 = 0.f, s1 = 0.f, s2 = 0.f, s3 = 0.f, d = 0.f;
    for (int js = 0; js < jsn; ++js) {
        f16x4 v = *(const f16x4*)(num + ((size_t)js * NN + i) * HF + c4);
        s0 += (float)v[0]; s1 += (float)v[1]; s2 += (float)v[2]; s3 += (float)v[3];
        d += den[((size_t)js * NHD + h) * NN + i];
    }
    float inv = 1.0f / d;
    float4 b = *(const float4*)(bias + c4);
    float4 o;
    o.x = s0 * inv + b.x; o.y = s1 * inv + b.y;
    o.z = s2 * inv + b.z; o.w = s3 * inv + b.w;
    *(float4*)(out + (size_t)i * HF + c4) = o;
}

extern "C" void kernel_launch(void* const* d_in, const int* in_sizes, int n_in,
                              void* d_out, int out_size, void* d_ws, size_t ws_size,
                              hipStream_t stream) {
    const float* x    = (const float*)d_in[0];
    const float* adj  = (const float*)d_in[1];
    const float* W    = (const float*)d_in[2];
    const float* ai   = (const float*)d_in[3];
    const float* aj   = (const float*)d_in[4];
    const float* bias = (const float*)d_in[5];
    float* out = (float*)d_out;

    int jsn = 4, jsh = 2;

    char* ws = (char*)d_ws;
    __bf16*   hbT = (__bf16*)(ws);                               // 4,259,840 B used
    float*    ci  = (float*)(ws + 4456448);                      // 64 KB
    float*    cj  = (float*)(ws + 4521984);                      // 64 KB
    __bf16*   WTp = (__bf16*)(ws + 4587520);                     // 256 KB (fragment-major)
    float*    den = (float*)(ws + 4849664);                      // jsn*64 KB
    _Float16* num = (_Float16*)(ws + 4849664 + (size_t)jsn * 65536);  // jsn*4 MB

    k_transpose_w<<<dim3(4, 8), 256, 0, stream>>>(W, WTp);
    k_gemm_h<<<dim3(256, 4), 256, 0, stream>>>(x, WTp, ai, aj, hbT, ci, cj);
    k_attn<<<jsn * 64, 512, 0, stream>>>(adj, hbT, ci, cj, num, den, jsn - 1, jsh);
    k_reduce<<<2048, 256, 0, stream>>>(num, den, bias, out, jsn);
}

// Round 13
// 160.524 us; speedup vs baseline: 1.1979x; 1.0852x over previous
//
#include <hip/hip_runtime.h>
#include <hip/hip_bf16.h>

#define NN 4096
#define KIN 256
#define HF 512
#define NHD 4
#define OF 128
#define JP 4160            // padded hbT row stride (8320 B: non-pow2 channel spread)

typedef __bf16 bf16x8 __attribute__((ext_vector_type(8)));
typedef __bf16 bf16x4 __attribute__((ext_vector_type(4)));
typedef float f32x4 __attribute__((ext_vector_type(4)));
typedef _Float16 f16x4 __attribute__((ext_vector_type(4)));

// async 16B/lane global->LDS: dest = wave-uniform LDS base + lane*16,
// src = per-lane global address. In-flight state lives in the vmem queue,
// NOT in VGPRs (the ~128-reg allocator ceiling re-serializes reg-based MLP).
__device__ __forceinline__ void glds16(const void* g, void* l) {
    __builtin_amdgcn_global_load_lds(
        (const __attribute__((address_space(1))) void*)g,
        (__attribute__((address_space(3))) void*)l, 16, 0, 0);
}

// ---------------- K0: W -> WTp, FRAGMENT-MAJOR pack ----------------
// WTp[((t*8+kk)*64+lane)*8 + e] = W[kk*32+(lane>>4)*8+e][t*16+(lane&15)]
// i.e. exactly the bf16x8 B-fragment K1's wave needs, contiguous per wave.
__global__ __launch_bounds__(256) void k_transpose_w(const float* __restrict__ W,
                                                     __bf16* __restrict__ WTp) {
    __shared__ __bf16 tl[64][65];
    int k0 = blockIdx.x * 64, c0 = blockIdx.y * 64;
    #pragma unroll
    for (int it = 0; it < 16; ++it) {
        int idx = it * 256 + threadIdx.x;
        int kk = idx >> 6, cc = idx & 63;
        tl[kk][cc] = (__bf16)W[(size_t)(k0 + kk) * HF + c0 + cc];
    }
    __syncthreads();
    int lane = threadIdx.x & 63, f0 = threadIdx.x >> 6;   // f0 = local c-tile 0..3
    int q = lane >> 4, r = lane & 15;
    #pragma unroll
    for (int kkf = 0; kkf < 2; ++kkf) {                   // two 32-k chunks in tile
        bf16x8 o;
        #pragma unroll
        for (int e = 0; e < 8; ++e)
            o[e] = tl[kkf * 32 + q * 8 + e][f0 * 16 + r];
        int t_g = (c0 >> 4) + f0;
        int kk_g = (k0 >> 5) + kkf;
        *(bf16x8*)(WTp + ((size_t)(t_g * 8 + kk_g) * 64 + lane) * 8) = o;
    }
}

// ------- K1: gemm (hbT) + fused ci/cj — de-diverged (round 11) -------
// grid (256 node-tiles, 4 h), 256 thr = 4 waves. x staged once via glds16;
// WT fragments are contiguous 1KB bursts from WTp. UNCHANGED this round.
__global__ __launch_bounds__(256) void k_gemm_h(const float* __restrict__ x,
                                                const __bf16* __restrict__ WTp,
                                                const float* __restrict__ ai,
                                                const float* __restrict__ aj,
                                                __bf16* __restrict__ hbT,
                                                float* __restrict__ ci,
                                                float* __restrict__ cj) {
    __shared__ float xs[16][257];
    __shared__ float credi[4][16], credj[4][16];
    int tid = threadIdx.x, lane = tid & 63, w = tid >> 6;
    int r = lane & 15, q = lane >> 4;
    int m0 = blockIdx.x * 16;
    int h = blockIdx.y;

    #pragma unroll
    for (int k = 0; k < 4; ++k) {
        int row = w * 4 + k;
        glds16(x + (size_t)(m0 + row) * KIN + 4 * lane, &xs[row][0]);
    }
    asm volatile("s_waitcnt vmcnt(0)" ::: "memory");
    __syncthreads();

    f32x4 acc[2];
    #pragma unroll
    for (int nt = 0; nt < 2; ++nt) acc[nt] = (f32x4){0.f, 0.f, 0.f, 0.f};
    const __bf16* wp = WTp + ((size_t)(h * 8 + w * 2) * 8 * 64 + lane) * 8;
    #pragma unroll
    for (int kk = 0; kk < 8; ++kk) {
        float4 xa = *(const float4*)&xs[r][kk * 32 + q * 8];
        float4 xb = *(const float4*)&xs[r][kk * 32 + q * 8 + 4];
        bf16x8 af;
        af[0] = (__bf16)xa.x; af[1] = (__bf16)xa.y; af[2] = (__bf16)xa.z; af[3] = (__bf16)xa.w;
        af[4] = (__bf16)xb.x; af[5] = (__bf16)xb.y; af[6] = (__bf16)xb.z; af[7] = (__bf16)xb.w;
        #pragma unroll
        for (int nt = 0; nt < 2; ++nt) {
            bf16x8 bf = *(const bf16x8*)(wp + nt * 4096 + kk * 512);
            acc[nt] = __builtin_amdgcn_mfma_f32_16x16x32_bf16(af, bf, acc[nt], 0, 0, 0);
        }
    }
    float pi[4] = {0.f, 0.f, 0.f, 0.f}, pj[4] = {0.f, 0.f, 0.f, 0.f};
    #pragma unroll
    for (int nt = 0; nt < 2; ++nt) {
        int c = h * 128 + w * 32 + nt * 16 + r;
        float av = ai[c], jv = aj[c];
        bf16x4 o;
        #pragma unroll
        for (int e = 0; e < 4; ++e) {
            o[e] = (__bf16)acc[nt][e];
            pi[e] += av * acc[nt][e];
            pj[e] += jv * acc[nt][e];
        }
        *(bf16x4*)(hbT + (size_t)c * JP + m0 + q * 4) = o;
    }
    #pragma unroll
    for (int off = 1; off < 16; off <<= 1)
        #pragma unroll
        for (int e = 0; e < 4; ++e) {
            pi[e] += __shfl_xor(pi[e], off);
            pj[e] += __shfl_xor(pj[e], off);
        }
    if (r == 0)
        #pragma unroll
        for (int e = 0; e < 4; ++e) {
            credi[w][q * 4 + e] = pi[e];
            credj[w][q * 4 + e] = pj[e];
        }
    __syncthreads();
    if (tid < 16) {
        ci[h * NN + m0 + tid] = credi[0][tid] + credi[1][tid] + credi[2][tid] + credi[3][tid];
    } else if (tid >= 64 && tid < 80) {
        int nl = tid - 64;
        cj[h * NN + m0 + nl] = credj[0][nl] + credj[1][nl] + credj[2][nl] + credj[3][nl];
    }
}

// ---------------- K3: fused attention — round-9 structure, 2 blocks/CU ----------------
// jsn=8 -> grid 512 -> TWO co-resident 80 KB blocks per CU
// (2 x 81920 B = exactly the 160 KiB pool; VGPR=64 fits easily).
// 4 waves/SIMD: when one block parks at its staging barrier, the other
// block's waves fill the SIMD -> latency/barrier stalls overlapped.
__global__ __launch_bounds__(512) void k_attn(const float* __restrict__ adj,
                                              const __bf16* __restrict__ hbT,
                                              const float* __restrict__ ci,
                                              const float* __restrict__ cj,
                                              _Float16* __restrict__ num,
                                              float* __restrict__ den,
                                              int jmask, int jsh) {
    __shared__ __bf16 vt[2][512][32];    // [buf][h*128+ch][j-slot swizzled]
    __shared__ float  ats[2][64][32];    // [buf][i-local][j-slot swizzled]
    int tid = threadIdx.x, lane = tid & 63, w = tid >> 6;
    int h = w & 3, rg = w >> 2;
    int m = lane & 15, q = lane >> 4;
    int bid = blockIdx.x;
    int js = bid & jmask;
    int i0 = (bid >> jsh) << 6;
    int jb = js << (12 - jsh);          // slice width = NN >> jsh
    int nch = 1 << (7 - jsh);           // chunks of 32 j per slice

    const __bf16* vS[4];
    #pragma unroll
    for (int k = 0; k < 4; ++k) {
        int t = (w * 4 + k) * 16 + (lane >> 2);
        vS[k] = hbT + (size_t)t * JP + jb + (((lane & 3) ^ (t & 3)) * 8);
    }
    int il = w * 8 + (lane >> 3);
    const float* aS = adj + (size_t)(i0 + il) * NN + jb + (((lane & 7) ^ (il & 7)) * 4);
    const float* cjsrc = cj + (size_t)h * NN + jb + q * 8;

    float civ0 = ci[h * NN + i0 + rg * 32 + m];
    float civ1 = ci[h * NN + i0 + rg * 32 + 16 + m];

    f32x4 acc[2][8];
    #pragma unroll
    for (int g = 0; g < 2; ++g)
        #pragma unroll
        for (int nt = 0; nt < 8; ++nt) acc[g][nt] = (f32x4){0.f, 0.f, 0.f, 0.f};
    float den0 = 0.f, den1 = 0.f;

    #pragma unroll
    for (int k = 0; k < 4; ++k) glds16(vS[k], &vt[0][(w * 4 + k) * 16][0]);
    glds16(aS, &ats[0][w * 8][0]);
    float4 pc0 = *(const float4*)(cjsrc);
    float4 pc1 = *(const float4*)(cjsrc + 4);

    int ir0 = rg * 32 + m;
    int sA0 = ((2 * q + 0) ^ (m & 7)) * 4;
    int sA1 = ((2 * q + 1) ^ (m & 7)) * 4;
    int sV  = (q ^ (m & 3)) * 8;

    for (int c = 0; c < nch; ++c) {
        int cb = c & 1, nb = cb ^ 1;
        if (c + 1 < nch) {
            #pragma unroll
            for (int k = 0; k < 4; ++k)
                glds16(vS[k] + (size_t)(c + 1) * 32, &vt[nb][(w * 4 + k) * 16][0]);
            glds16(aS + (size_t)(c + 1) * 32, &ats[nb][w * 8][0]);
            asm volatile("s_waitcnt vmcnt(7)" ::: "memory");
        } else {
            asm volatile("s_waitcnt vmcnt(0)" ::: "memory");
        }
        __builtin_amdgcn_s_barrier();
        asm volatile("" ::: "memory");

        float4 x00 = *(const float4*)&ats[cb][ir0][sA0];
        float4 x01 = *(const float4*)&ats[cb][ir0][sA1];
        float4 x10 = *(const float4*)&ats[cb][ir0 + 16][sA0];
        float4 x11 = *(const float4*)&ats[cb][ir0 + 16][sA1];
        float ccv[8];
        ccv[0] = pc0.x; ccv[1] = pc0.y; ccv[2] = pc0.z; ccv[3] = pc0.w;
        ccv[4] = pc1.x; ccv[5] = pc1.y; ccv[6] = pc1.z; ccv[7] = pc1.w;
        float aa0[8], aa1[8];
        aa0[0] = x00.x; aa0[1] = x00.y; aa0[2] = x00.z; aa0[3] = x00.w;
        aa0[4] = x01.x; aa0[5] = x01.y; aa0[6] = x01.z; aa0[7] = x01.w;
        aa1[0] = x10.x; aa1[1] = x10.y; aa1[2] = x10.z; aa1[3] = x10.w;
        aa1[4] = x11.x; aa1[5] = x11.y; aa1[6] = x11.z; aa1[7] = x11.w;

        bf16x8 af0, af1;
        #pragma unroll
        for (int u = 0; u < 8; ++u) {
            float a = aa0[u];
            float s = civ0 + ccv[u];
            s = fmaxf(s, s * 0.2f);     // leaky_relu
            s *= a;
            float p = __expf(s);        // s in ~[-4,4]: shift-free softmax safe
            den0 += p;
            af0[u] = (__bf16)(p * a);
        }
        #pragma unroll
        for (int u = 0; u < 8; ++u) {
            float a = aa1[u];
            float s = civ1 + ccv[u];
            s = fmaxf(s, s * 0.2f);
            s *= a;
            float p = __expf(s);
            den1 += p;
            af1[u] = (__bf16)(p * a);
        }
        if (c + 1 < nch) {
            pc0 = *(const float4*)(cjsrc + (c + 1) * 32);
            pc1 = *(const float4*)(cjsrc + (c + 1) * 32 + 4);
        }
        #pragma unroll
        for (int nt = 0; nt < 8; ++nt) {
            bf16x8 bfv = *(const bf16x8*)&vt[cb][h * 128 + nt * 16 + m][sV];
            acc[0][nt] = __builtin_amdgcn_mfma_f32_16x16x32_bf16(af0, bfv, acc[0][nt], 0, 0, 0);
            acc[1][nt] = __builtin_amdgcn_mfma_f32_16x16x32_bf16(af1, bfv, acc[1][nt], 0, 0, 0);
        }
        asm volatile("" ::: "memory");
        __builtin_amdgcn_s_barrier();
    }
    den0 += __shfl_xor(den0, 16); den0 += __shfl_xor(den0, 32);
    den1 += __shfl_xor(den1, 16); den1 += __shfl_xor(den1, 32);
    if (lane < 16) {
        float* dp = den + ((size_t)js * NHD + h) * NN + i0 + rg * 32;
        dp[lane] = den0;
        dp[16 + lane] = den1;
    }
    #pragma unroll
    for (int g = 0; g < 2; ++g)
        #pragma unroll
        for (int nt = 0; nt < 8; ++nt)
            #pragma unroll
            for (int reg = 0; reg < 4; ++reg) {
                int i = i0 + rg * 32 + g * 16 + q * 4 + reg;
                num[((size_t)js * NN + i) * HF + h * OF + nt * 16 + m] =
                    (_Float16)acc[g][nt][reg];
            }
}

// ---------------- K4: reduce jsn partials, divide, +bias, fp32 out ---------
__global__ __launch_bounds__(256) void k_reduce(const _Float16* __restrict__ num,
                                               const float* __restrict__ den,
                                               const float* __restrict__ bias,
                                               float* __restrict__ out,
                                               int jsn) {
    int g = blockIdx.x * 256 + threadIdx.x;    // NN*HF/4 groups
    int i = g >> 7, c4 = (g & 127) << 2;
    int h = c4 >> 7;
    float s0 = 0.f, s1 = 0.f, s2 = 0.f, s3 = 0.f, d = 0.f;
    for (int js = 0; js < jsn; ++js) {
        f16x4 v = *(const f16x4*)(num + ((size_t)js * NN + i) * HF + c4);
        s0 += (float)v[0]; s1 += (float)v[1]; s2 += (float)v[2]; s3 += (float)v[3];
        d += den[((size_t)js * NHD + h) * NN + i];
    }
    float inv = 1.0f / d;
    float4 b = *(const float4*)(bias + c4);
    float4 o;
    o.x = s0 * inv + b.x; o.y = s1 * inv + b.y;
    o.z = s2 * inv + b.z; o.w = s3 * inv + b.w;
    *(float4*)(out + (size_t)i * HF + c4) = o;
}

extern "C" void kernel_launch(void* const* d_in, const int* in_sizes, int n_in,
                              void* d_out, int out_size, void* d_ws, size_t ws_size,
                              hipStream_t stream) {
    const float* x    = (const float*)d_in[0];
    const float* adj  = (const float*)d_in[1];
    const float* W    = (const float*)d_in[2];
    const float* ai   = (const float*)d_in[3];
    const float* aj   = (const float*)d_in[4];
    const float* bias = (const float*)d_in[5];
    float* out = (float*)d_out;

    // jsn=8 -> grid 512 -> 2 co-resident 80 KB blocks/CU (TLP).
    // Needs den 512 KB + num 32 MB; fall back to 4 if workspace is tight.
    int jsn = (ws_size >= (size_t)38928384) ? 8 : 4;
    int jsh = (jsn == 8) ? 3 : 2;

    char* ws = (char*)d_ws;
    __bf16*   hbT = (__bf16*)(ws);                               // 4,259,840 B used
    float*    ci  = (float*)(ws + 4456448);                      // 64 KB
    float*    cj  = (float*)(ws + 4521984);                      // 64 KB
    __bf16*   WTp = (__bf16*)(ws + 4587520);                     // 256 KB (fragment-major)
    float*    den = (float*)(ws + 4849664);                      // jsn*64 KB
    _Float16* num = (_Float16*)(ws + 4849664 + (size_t)jsn * 65536);  // jsn*4 MB

    k_transpose_w<<<dim3(4, 8), 256, 0, stream>>>(W, WTp);
    k_gemm_h<<<dim3(256, 4), 256, 0, stream>>>(x, WTp, ai, aj, hbT, ci, cj);
    k_attn<<<jsn * 64, 512, 0, stream>>>(adj, hbT, ci, cj, num, den, jsn - 1, jsh);
    k_reduce<<<2048, 256, 0, stream>>>(num, den, bias, out, jsn);
}